// Round 19
// baseline (44490.955 us; speedup 1.0000x reference)
//
#include <hip/hip_runtime.h>
#include <hip/hip_bf16.h>

#define V_ 16000
#define L_ 12
#define K_ 512
#define LOST_ 512
#define D_ 128

constexpr float CW = 0.5f;
constexpr float IDC = 3.5f;

// FIX (round 19): d_out is FLOAT32, not bf16 — proven by out_npz_mb=514.6 MB >
// 393.7 MB (the bf16 raw size of 196.9M output elements). All prior rounds
// wrote bf16 pairs into f32 slots, which decorrelated the comparison
// regardless of content. Content semantics are round-3 (displayed reference).

__device__ __align__(16) float g_lost[LOST_ * D_];   // lost_unit_emb [512][128]
__device__ __align__(16) float g_ulp[K_ * LOST_];    // unit_log_probs [512][512]

// ---------------- kernel 1: lost_emb = aligner @ E   [LOST][D]
__global__ __launch_bounds__(128) void k_lost(const float* __restrict__ W,
                                              const float* __restrict__ E) {
    int m = blockIdx.x;      // lost index
    int d = threadIdx.x;     // emb dim
    const float* wrow = W + (size_t)m * K_;
    float acc = 0.f;
    for (int k = 0; k < K_; ++k) acc = fmaf(wrow[k], E[k * D_ + d], acc);
    g_lost[m * D_ + d] = acc;
}

// ---------------- kernel 2: unit_log_probs [K][LOST] + alignment output (f32)
__global__ __launch_bounds__(512) void k_ulp(const float* __restrict__ E,
                                             float* __restrict__ align_out) {
    int k = blockIdx.x, t = threadIdx.x;   // t = lost index m
    __shared__ float e[D_];
    __shared__ float red[512];
    if (t < D_) e[t] = E[k * D_ + t];
    __syncthreads();
    float acc = 0.f;
    for (int d = 0; d < D_; ++d) acc = fmaf(e[d], g_lost[t * D_ + d], acc);
    red[t] = acc;
    __syncthreads();
    for (int s = 256; s; s >>= 1) {
        if (t < s) red[t] = fmaxf(red[t], red[t + s]);
        __syncthreads();
    }
    float bm = red[0];
    __syncthreads();
    red[t] = expf(acc - bm);
    __syncthreads();
    for (int s = 256; s; s >>= 1) {
        if (t < s) red[t] += red[t + s];
        __syncthreads();
    }
    float lp = acc - bm - logf(red[0]);
    g_ulp[(size_t)k * LOST_ + t] = lp;
    align_out[(size_t)k * LOST_ + t] = expf(lp);
}

// ---------------- kernel 3: fully naive per-(v,l,c) conv + logits + softmax + out (f32)
__global__ __launch_bounds__(128) void k_simple(const float* __restrict__ E,
                                                const float* __restrict__ convW,
                                                const float* __restrict__ convB,
                                                const float* __restrict__ insW,
                                                const float* __restrict__ insB,
                                                const int* __restrict__ ids,
                                                const int* __restrict__ lens,
                                                float* __restrict__ sub_out,
                                                float* __restrict__ ins_out) {
    int bid = blockIdx.x;            // v*24 + l*2 + c
    int c = bid & 1;
    int l = (bid >> 1) % 12;
    int v = bid / 24;
    int t = threadIdx.x;             // 0..127

    __shared__ float x[3][128];      // masked input rows l-1, l, l+1
    __shared__ float ctx[128];
    __shared__ float lgs[512];
    __shared__ float red[128];

    int len = min(max(lens[v], 0), 12);
    int sid = min(max(ids[v * 12 + l], 0), 511);

    // stage masked emb rows (zero outside [0,len))
#pragma unroll
    for (int r = 0; r < 3; ++r) {
        int ll = l + r - 1;
        float val = 0.f;
        if (ll >= 0 && ll < len) {
            int id = min(max(ids[v * 12 + ll], 0), 511);
            val = E[(size_t)id * D_ + t];
        }
        x[r][t] = val;
    }
    __syncthreads();

    // conv: thread t = dout. y = b + sum_{t3,di} x[t3][di] * w[dout][di][t3]
    const float* w = c ? insW : convW;
    float acc = c ? insB[t] : convB[t];
    for (int t3 = 0; t3 < 3; ++t3) {
        for (int di = 0; di < 128; ++di) {
            acc = fmaf(x[t3][di], w[((size_t)t * 128 + di) * 3 + t3], acc);
        }
    }
    ctx[t] = acc;
    __syncthreads();

    // logits: thread t computes m = j*128 + t for j=0..3
    float lgv[4];
#pragma unroll
    for (int j = 0; j < 4; ++j) {
        int m = j * 128 + t;
        const float* lm = g_lost + (size_t)m * D_;
        float a = 0.f;
        for (int d = 0; d < D_; ++d) a = fmaf(ctx[d], lm[d], a);
        lgs[m] = a;
        lgv[j] = a;
    }
    __syncthreads();

    // block max over 512
    float mx = fmaxf(fmaxf(lgs[t], lgs[t + 128]), fmaxf(lgs[t + 256], lgs[t + 384]));
    red[t] = mx;
    __syncthreads();
    for (int s = 64; s; s >>= 1) {
        if (t < s) red[t] = fmaxf(red[t], red[t + s]);
        __syncthreads();
    }
    float bm = red[0];
    __syncthreads();

    // block sum of exp
    float sm = 0.f;
#pragma unroll
    for (int j = 0; j < 4; ++j) sm += expf(lgv[j] - bm);
    red[t] = sm;
    __syncthreads();
    for (int s = 64; s; s >>= 1) {
        if (t < s) red[t] += red[t + s];
        __syncthreads();
    }
    float norm = bm + logf(red[0]);

    size_t base = ((size_t)v * 12 + l) * 512;
    if (c == 0) {
        const float* gl = g_ulp + (size_t)sid * LOST_;
#pragma unroll
        for (int j = 0; j < 4; ++j) {
            int m = j * 128 + t;
            float lp = lgv[j] - norm;
            sub_out[base + m] = -(CW * lp + (1.f - CW) * gl[m]);
        }
    } else {
#pragma unroll
        for (int j = 0; j < 4; ++j) {
            int m = j * 128 + t;
            float lp = lgv[j] - norm;
            ins_out[base + m] = IDC - CW * lp;
        }
    }
}

extern "C" void kernel_launch(void* const* d_in, const int* in_sizes, int n_in,
                              void* d_out, int out_size, void* d_ws, size_t ws_size,
                              hipStream_t stream) {
    const float* E = (const float*)d_in[0];         // known_unit_emb [512][128]
    const float* W = (const float*)d_in[1];         // unit_aligner_weight [512][512]
    const float* convW = (const float*)d_in[2];     // [128][128][3]
    const float* convB = (const float*)d_in[3];     // [128]
    const float* insW = (const float*)d_in[4];
    const float* insB = (const float*)d_in[5];
    const int* ids = (const int*)d_in[6];           // [16000][12]
    const int* lens = (const int*)d_in[7];          // [16000]

    float* out = (float*)d_out;                                // FLOAT32 output
    float* sub_out = out;                                      // slot 0: [V][L][512]
    float* ins_out = out + (size_t)V_ * L_ * LOST_;            // slot 1: [V][L][512]
    float* align_out = out + 2ull * V_ * L_ * LOST_;           // slot 2: [512][512]

    hipLaunchKernelGGL(k_lost, dim3(LOST_), dim3(128), 0, stream, W, E);
    hipLaunchKernelGGL(k_ulp, dim3(K_), dim3(512), 0, stream, E, align_out);
    hipLaunchKernelGGL(k_simple, dim3(V_ * 12 * 2), dim3(128), 0, stream,
                       E, convW, convB, insW, insB, ids, lens, sub_out, ins_out);
}

// Round 20
// 1895.851 us; speedup vs baseline: 23.4675x; 23.4675x over previous
//
#include <hip/hip_runtime.h>
#include <hip/hip_bf16.h>

#define V_ 16000
#define L_ 12
#define K_ 512
#define LOST_ 512
#define D_ 128

constexpr float CW = 0.5f;
constexpr float IDC = 3.5f;

__device__ __align__(16) float g_wr[2 * 3 * 128 * 128];   // repacked conv weights [c][t3][di][dout]
__device__ __align__(16) float g_lost[LOST_ * D_];        // lost_unit_emb [512][128]
__device__ __align__(16) float g_ulp[K_ * LOST_];         // unit_log_probs [512][512]

// ---------------- kernel 0: repack conv weights [do][di][t3] -> [c][t3][di][do]
__global__ __launch_bounds__(256) void k_repack(const float* __restrict__ wA,
                                                const float* __restrict__ wB) {
    int idx = blockIdx.x * 256 + threadIdx.x;
    if (idx >= 2 * 3 * 128 * 128) return;
    int dout = idx & 127;
    int di = (idx >> 7) & 127;
    int rem = idx >> 14;          // c*3 + t3
    int t3 = rem % 3;
    int c = rem / 3;
    const float* w = c ? wB : wA;
    g_wr[idx] = w[(dout * 128 + di) * 3 + t3];
}

// ---------------- kernel 1: lost_emb = aligner @ E   [LOST][D]
__global__ __launch_bounds__(128) void k_lost(const float* __restrict__ W,
                                              const float* __restrict__ E) {
    int m = blockIdx.x;
    int d = threadIdx.x;
    const float* wrow = W + (size_t)m * K_;
    float acc = 0.f;
    for (int k = 0; k < K_; ++k) acc = fmaf(wrow[k], E[k * D_ + d], acc);
    g_lost[m * D_ + d] = acc;
}

// ---------------- kernel 2: unit_log_probs + alignment output (f32)
__global__ __launch_bounds__(512) void k_ulp(const float* __restrict__ E,
                                             float* __restrict__ align_out) {
    int k = blockIdx.x, t = threadIdx.x;
    __shared__ float e[D_];
    __shared__ float red[8];
    if (t < D_) e[t] = E[k * D_ + t];
    __syncthreads();
    const float* lm = g_lost + (size_t)t * D_;
    float acc = 0.f;
    for (int d = 0; d < D_; d += 4) {
        float4 lv = *(const float4*)(lm + d);
        acc = fmaf(e[d], lv.x, acc);
        acc = fmaf(e[d + 1], lv.y, acc);
        acc = fmaf(e[d + 2], lv.z, acc);
        acc = fmaf(e[d + 3], lv.w, acc);
    }
    int lane = t & 63, wid = t >> 6;
    float wm = acc;
    for (int off = 32; off; off >>= 1) wm = fmaxf(wm, __shfl_xor(wm, off, 64));
    if (lane == 0) red[wid] = wm;
    __syncthreads();
    float bm = red[0];
#pragma unroll
    for (int i = 1; i < 8; ++i) bm = fmaxf(bm, red[i]);
    __syncthreads();
    float s = expf(acc - bm);
    for (int off = 32; off; off >>= 1) s += __shfl_xor(s, off, 64);
    if (lane == 0) red[wid] = s;
    __syncthreads();
    float bs = 0.f;
#pragma unroll
    for (int i = 0; i < 8; ++i) bs += red[i];
    float lp = acc - bm - logf(bs);
    g_ulp[(size_t)k * LOST_ + t] = lp;
    align_out[(size_t)k * LOST_ + t] = expf(lp);
}

// ---------------- kernel 3: fused per-v kernel (256 threads, 4 waves)
__global__ __launch_bounds__(256) void k_main(const float* __restrict__ E,
                                              const float* __restrict__ bA,
                                              const float* __restrict__ bB,
                                              const int* __restrict__ ids,
                                              const int* __restrict__ lens,
                                              float* __restrict__ sub_out,
                                              float* __restrict__ ins_out) {
    __shared__ float emb[14 * 128];      // rows 0 and 13 zero pads; row r = seq pos r-1
    __shared__ float ctx[2 * 12 * 128];  // [c][l][dout]
    __shared__ float ltile[64 * 128];    // swizzled lost tile
    __shared__ int sids[12];
    __shared__ int slen;

    int v = blockIdx.x;
    int t = threadIdx.x;
    int lane = t & 63, wid = t >> 6;

    if (t < 12) sids[t] = min(max(ids[v * 12 + t], 0), 511);
    if (t == 12) slen = min(max(lens[v], 0), 12);
    __syncthreads();

    // ---- gather masked emb rows
    int len = slen;
#pragma unroll
    for (int i = 0; i < 7; ++i) {
        int e = t + i * 256;             // 0..1791
        int row = e >> 7, d = e & 127;
        float val = 0.f;
        if (row >= 1 && row <= 12) {
            int l = row - 1;
            if (l < len) val = E[(size_t)sids[l] * D_ + d];
        }
        emb[row * 128 + d] = val;
    }
    __syncthreads();

    // ---- conv: thread = (c = t>>7, dout = t&127), all 12 l's
    {
        int dout = t & 127, c = t >> 7;
        float acc[12];
        float bias = c ? bB[dout] : bA[dout];
#pragma unroll
        for (int l = 0; l < 12; ++l) acc[l] = bias;
        const float* wr = g_wr + c * (3 * 128 * 128);   // [t3][di][dout]
        for (int di4 = 0; di4 < 32; ++di4) {
            float er[14][4];
#pragma unroll
            for (int r = 0; r < 14; ++r) {
                float4 e4 = *(const float4*)(&emb[r * 128 + di4 * 4]);
                er[r][0] = e4.x; er[r][1] = e4.y; er[r][2] = e4.z; er[r][3] = e4.w;
            }
#pragma unroll
            for (int dd = 0; dd < 4; ++dd) {
                int di = di4 * 4 + dd;
#pragma unroll
                for (int t3 = 0; t3 < 3; ++t3) {
                    float w = wr[(t3 * 128 + di) * 128 + dout];
#pragma unroll
                    for (int l = 0; l < 12; ++l)
                        acc[l] = fmaf(er[l + t3][dd], w, acc[l]);
                }
            }
        }
#pragma unroll
        for (int l = 0; l < 12; ++l) ctx[(c * 12 + l) * 128 + dout] = acc[l];
    }

    // ---- logits: wave wid owns 6 (c,l) pairs; lane owns m = jt*64 + lane
    int c = wid >> 1, lb = (wid & 1) * 6;
    const float* ctxw = ctx + (c * 12 + lb) * 128;   // [6][128]
    float acc2[6][8];
#pragma unroll
    for (int q = 0; q < 6; ++q)
#pragma unroll
        for (int j = 0; j < 8; ++j) acc2[q][j] = 0.f;

#pragma unroll
    for (int jt = 0; jt < 8; ++jt) {
        __syncthreads();   // protect prior tile reads (and at jt=0, ctx writes)
#pragma unroll
        for (int i = 0; i < 8; ++i) {
            int q4 = t + i * 256;        // float4 chunk of the 64x128 tile
            int row = q4 >> 5, c4 = q4 & 31;
            float4 lv = *(const float4*)(g_lost + ((size_t)(jt * 64 + row)) * 128 + c4 * 4);
            *(float4*)(ltile + row * 128 + ((c4 ^ (row & 7)) << 2)) = lv;
        }
        __syncthreads();
        for (int d4 = 0; d4 < 32; ++d4) {
            float4 lv = *(const float4*)(ltile + lane * 128 + ((d4 ^ (lane & 7)) << 2));
#pragma unroll
            for (int q = 0; q < 6; ++q) {
                float4 cv = *(const float4*)(ctxw + q * 128 + d4 * 4);
                acc2[q][jt] = fmaf(cv.x, lv.x, acc2[q][jt]);
                acc2[q][jt] = fmaf(cv.y, lv.y, acc2[q][jt]);
                acc2[q][jt] = fmaf(cv.z, lv.z, acc2[q][jt]);
                acc2[q][jt] = fmaf(cv.w, lv.w, acc2[q][jt]);
            }
        }
    }

    // ---- wave-local softmax per (c,l) + f32 output
#pragma unroll
    for (int q = 0; q < 6; ++q) {
        int ll = lb + q;
        float mx = acc2[q][0];
#pragma unroll
        for (int j = 1; j < 8; ++j) mx = fmaxf(mx, acc2[q][j]);
        for (int off = 32; off; off >>= 1) mx = fmaxf(mx, __shfl_xor(mx, off, 64));
        float s = 0.f;
#pragma unroll
        for (int j = 0; j < 8; ++j) s += expf(acc2[q][j] - mx);
        for (int off = 32; off; off >>= 1) s += __shfl_xor(s, off, 64);
        float norm = mx + logf(s);
        size_t base = ((size_t)v * 12 + ll) * 512;
        if (c == 0) {
            const float* gl = g_ulp + (size_t)sids[ll] * LOST_;
#pragma unroll
            for (int j = 0; j < 8; ++j) {
                float lp = acc2[q][j] - norm;
                sub_out[base + j * 64 + lane] = -(CW * lp + (1.f - CW) * gl[j * 64 + lane]);
            }
        } else {
#pragma unroll
            for (int j = 0; j < 8; ++j) {
                float lp = acc2[q][j] - norm;
                ins_out[base + j * 64 + lane] = IDC - CW * lp;
            }
        }
    }
}

extern "C" void kernel_launch(void* const* d_in, const int* in_sizes, int n_in,
                              void* d_out, int out_size, void* d_ws, size_t ws_size,
                              hipStream_t stream) {
    const float* E = (const float*)d_in[0];         // known_unit_emb [512][128]
    const float* W = (const float*)d_in[1];         // unit_aligner_weight [512][512]
    const float* convW = (const float*)d_in[2];     // [128][128][3]
    const float* convB = (const float*)d_in[3];     // [128]
    const float* insW = (const float*)d_in[4];
    const float* insB = (const float*)d_in[5];
    const int* ids = (const int*)d_in[6];           // [16000][12]
    const int* lens = (const int*)d_in[7];          // [16000]

    float* out = (float*)d_out;                                // FLOAT32 output
    float* sub_out = out;                                      // [V][L][512]
    float* ins_out = out + (size_t)V_ * L_ * LOST_;            // [V][L][512]
    float* align_out = out + 2ull * V_ * L_ * LOST_;           // [512][512]

    hipLaunchKernelGGL(k_repack, dim3((2 * 3 * 128 * 128 + 255) / 256), dim3(256), 0, stream,
                       convW, insW);
    hipLaunchKernelGGL(k_lost, dim3(LOST_), dim3(128), 0, stream, W, E);
    hipLaunchKernelGGL(k_ulp, dim3(K_), dim3(512), 0, stream, E, align_out);
    hipLaunchKernelGGL(k_main, dim3(V_), dim3(256), 0, stream,
                       E, convB, insB, ids, lens, sub_out, ins_out);
}

// Round 21
// 900.988 us; speedup vs baseline: 49.3802x; 2.1042x over previous
//
#include <hip/hip_runtime.h>
#include <hip/hip_bf16.h>

#define V_ 16000
#define L_ 12
#define K_ 512
#define LOST_ 512
#define D_ 128

constexpr float CW = 0.5f;
constexpr float IDC = 3.5f;

typedef __attribute__((ext_vector_type(8))) short bf16x8;
typedef __attribute__((ext_vector_type(4))) float f32x4;

__device__ __align__(16) float g_lost[LOST_ * D_];    // lost_unit_emb f32 [512][128]
__device__ __align__(16) short g_lost_bf[LOST_ * D_]; // bf16 copy, [m][d] k-contiguous
__device__ __align__(16) float g_ulp[K_ * LOST_];     // unit_log_probs [512][512]
__device__ __align__(16) short g_wcv[2 * 128 * 384];  // conv weights bf16 [c][dout][t3*128+di]

__device__ __forceinline__ short f2b(float x) {
    __hip_bfloat16 h = __float2bfloat16(x);
    return *reinterpret_cast<short*>(&h);
}

// ---------------- kernel 0: repack conv weights -> bf16 [c][dout][k], k=t3*128+di
__global__ __launch_bounds__(256) void k_wcv(const float* __restrict__ wA,
                                             const float* __restrict__ wB) {
    int idx = blockIdx.x * 256 + threadIdx.x;       // (c*128+dout)*384 + t3*128 + di
    if (idx >= 2 * 128 * 384) return;
    int di = idx % 128;
    int t3 = (idx / 128) % 3;
    int dout = (idx / 384) % 128;
    int c = idx / (128 * 384);
    const float* w = c ? wB : wA;
    g_wcv[idx] = f2b(w[((size_t)dout * 128 + di) * 3 + t3]);
}

// ---------------- kernel 1: lost_emb = aligner @ E (f32 + bf16)
__global__ __launch_bounds__(128) void k_lost(const float* __restrict__ W,
                                              const float* __restrict__ E) {
    int m = blockIdx.x;
    int d = threadIdx.x;
    const float* wrow = W + (size_t)m * K_;
    float acc = 0.f;
    for (int k = 0; k < K_; ++k) acc = fmaf(wrow[k], E[k * D_ + d], acc);
    g_lost[m * D_ + d] = acc;
    g_lost_bf[m * D_ + d] = f2b(acc);
}

// ---------------- kernel 2: unit_log_probs + alignment output (f32)
__global__ __launch_bounds__(512) void k_ulp(const float* __restrict__ E,
                                             float* __restrict__ align_out) {
    int k = blockIdx.x, t = threadIdx.x;
    __shared__ float e[D_];
    __shared__ float red[8];
    if (t < D_) e[t] = E[k * D_ + t];
    __syncthreads();
    const float* lm = g_lost + (size_t)t * D_;
    float acc = 0.f;
    for (int d = 0; d < D_; d += 4) {
        float4 lv = *(const float4*)(lm + d);
        acc = fmaf(e[d], lv.x, acc);
        acc = fmaf(e[d + 1], lv.y, acc);
        acc = fmaf(e[d + 2], lv.z, acc);
        acc = fmaf(e[d + 3], lv.w, acc);
    }
    int lane = t & 63, wid = t >> 6;
    float wm = acc;
    for (int off = 32; off; off >>= 1) wm = fmaxf(wm, __shfl_xor(wm, off, 64));
    if (lane == 0) red[wid] = wm;
    __syncthreads();
    float bm = red[0];
#pragma unroll
    for (int i = 1; i < 8; ++i) bm = fmaxf(bm, red[i]);
    __syncthreads();
    float s = expf(acc - bm);
    for (int off = 32; off; off >>= 1) s += __shfl_xor(s, off, 64);
    if (lane == 0) red[wid] = s;
    __syncthreads();
    float bs = 0.f;
#pragma unroll
    for (int i = 0; i < 8; ++i) bs += red[i];
    float lp = acc - bm - logf(bs);
    g_ulp[(size_t)k * LOST_ + t] = lp;
    align_out[(size_t)k * LOST_ + t] = expf(lp);
}

// swizzled column: keep low 3 bits, XOR granule (bits 3..6) with row&7
__device__ __forceinline__ int swz(int col, int row) {
    return (col & 7) | ((((col >> 3) ^ (row & 7)) & 15) << 3);
}

// ---------------- kernel 3: fused MFMA per-v kernel (256 threads, 4 waves)
__global__ __launch_bounds__(256) void k_main(const float* __restrict__ E,
                                              const float* __restrict__ bA,
                                              const float* __restrict__ bB,
                                              const int* __restrict__ ids,
                                              const int* __restrict__ lens,
                                              float* __restrict__ sub_out,
                                              float* __restrict__ ins_out) {
    __shared__ short emb_bf[18][128];   // row r = seq pos r-1; rows 0,13..17 zero; swizzled
    __shared__ short ctx_bf[32][128];   // row r = c*12+l (r<24), rows 24..31 zero; swizzled
    __shared__ float redm[4][16];
    __shared__ float reds[4][16];
    __shared__ int sids[12];
    __shared__ int slen;

    int v = blockIdx.x;
    int t = threadIdx.x;
    int lane = t & 63, w = t >> 6;
    int l15 = lane & 15, kg = lane >> 4;

    if (t < 12) sids[t] = min(max(ids[v * 12 + t], 0), 511);
    if (t == 12) slen = min(max(lens[v], 0), 12);
    // zero pad rows of ctx (24..31)
    for (int i = t; i < 8 * 128; i += 256) ctx_bf[24 + (i >> 7)][i & 127] = 0;
    __syncthreads();
    int len = slen;

    // ---- gather masked emb rows -> bf16 swizzled LDS
    for (int i = t; i < 18 * 128; i += 256) {
        int row = i >> 7, di = i & 127;
        float val = 0.f;
        if (row >= 1 && row <= 12) {
            int pos = row - 1;
            if (pos < len) val = E[(size_t)sids[pos] * D_ + di];
        }
        emb_bf[row][swz(di, row)] = f2b(val);
    }
    __syncthreads();

    // ---- conv via MFMA: wave w -> c = w&1, dout-tiles dtb..dtb+3
    {
        int c = w & 1;
        int dtb = (w >> 1) * 4;
        f32x4 acc[4];
#pragma unroll
        for (int i = 0; i < 4; ++i) acc[i] = (f32x4){0.f, 0.f, 0.f, 0.f};
        const short* wb = g_wcv + (size_t)c * 128 * 384;
#pragma unroll
        for (int kk = 0; kk < 12; ++kk) {
            int t3 = kk >> 2;
            int row = l15 + t3;                       // emb row for A[l15][k]
            int g = (((kk & 3) * 4 + kg) ^ (row & 7)) & 15;
            bf16x8 af = *(const bf16x8*)&emb_bf[row][g << 3];
#pragma unroll
            for (int i = 0; i < 4; ++i) {
                int n = (dtb + i) * 16 + l15;
                bf16x8 bf = *(const bf16x8*)(wb + (size_t)n * 384 + kk * 32 + kg * 8);
                acc[i] = __builtin_amdgcn_mfma_f32_16x16x32_bf16(af, bf, acc[i], 0, 0, 0);
            }
        }
        // add bias, convert, store ctx rows r = c*12+l (swizzled)
#pragma unroll
        for (int i = 0; i < 4; ++i) {
            int dout = (dtb + i) * 16 + l15;
            float bias = (c ? bB : bA)[dout];
#pragma unroll
            for (int reg = 0; reg < 4; ++reg) {
                int lrow = kg * 4 + reg;              // C row = conv output l
                if (lrow < 12) {
                    int r = c * 12 + lrow;
                    ctx_bf[r][swz(dout, r)] = f2b(acc[i][reg] + bias);
                }
            }
        }
    }
    __syncthreads();

    // ---- logits via MFMA: wave w -> Mtile mt = w&1, N-half nh = w>>1
    int mt = w & 1, nh = w >> 1;
    f32x4 lacc[16];
#pragma unroll
    for (int i = 0; i < 16; ++i) lacc[i] = (f32x4){0.f, 0.f, 0.f, 0.f};
    int arow = mt * 16 + l15;
#pragma unroll
    for (int kk = 0; kk < 4; ++kk) {
        int g = ((kk * 4 + kg) ^ (arow & 7)) & 15;
        bf16x8 af = *(const bf16x8*)&ctx_bf[arow][g << 3];
        const short* lb = g_lost_bf + kk * 32 + kg * 8;
#pragma unroll
        for (int i = 0; i < 16; ++i) {
            int n = (nh * 16 + i) * 16 + l15;
            bf16x8 bf = *(const bf16x8*)(lb + (size_t)n * 128);
            lacc[i] = __builtin_amdgcn_mfma_f32_16x16x32_bf16(af, bf, lacc[i], 0, 0, 0);
        }
    }

    // ---- softmax: rows r = mt*16 + kg*4 + reg; cols split between wave pair (w, w^2)
    float fm[4], norm[4];
#pragma unroll
    for (int reg = 0; reg < 4; ++reg) {
        float m = lacc[0][reg];
#pragma unroll
        for (int i = 1; i < 16; ++i) m = fmaxf(m, lacc[i][reg]);
        for (int off = 1; off < 16; off <<= 1) m = fmaxf(m, __shfl_xor(m, off, 64));
        if (l15 == 0) redm[w][kg * 4 + reg] = m;
    }
    __syncthreads();
#pragma unroll
    for (int reg = 0; reg < 4; ++reg)
        fm[reg] = fmaxf(redm[w][kg * 4 + reg], redm[w ^ 2][kg * 4 + reg]);
#pragma unroll
    for (int reg = 0; reg < 4; ++reg) {
        float s = 0.f;
#pragma unroll
        for (int i = 0; i < 16; ++i) s += __expf(lacc[i][reg] - fm[reg]);
        for (int off = 1; off < 16; off <<= 1) s += __shfl_xor(s, off, 64);
        if (l15 == 0) reds[w][kg * 4 + reg] = s;
    }
    __syncthreads();
#pragma unroll
    for (int reg = 0; reg < 4; ++reg)
        norm[reg] = fm[reg] + __logf(reds[w][kg * 4 + reg] + reds[w ^ 2][kg * 4 + reg]);

    // ---- outputs (f32)
#pragma unroll
    for (int reg = 0; reg < 4; ++reg) {
        int r = mt * 16 + kg * 4 + reg;
        if (r >= 24) continue;
        int c = r / 12, ll = r % 12;
        size_t base = ((size_t)v * 12 + ll) * 512 + nh * 256;
        if (c == 0) {
            const float* gl = g_ulp + (size_t)sids[ll] * LOST_ + nh * 256;
#pragma unroll
            for (int i = 0; i < 16; ++i) {
                int col = i * 16 + l15;
                float lp = lacc[i][reg] - norm[reg];
                sub_out[base + col] = -(CW * lp + (1.f - CW) * gl[col]);
            }
        } else {
#pragma unroll
            for (int i = 0; i < 16; ++i) {
                int col = i * 16 + l15;
                float lp = lacc[i][reg] - norm[reg];
                ins_out[base + col] = IDC - CW * lp;
            }
        }
    }
}

extern "C" void kernel_launch(void* const* d_in, const int* in_sizes, int n_in,
                              void* d_out, int out_size, void* d_ws, size_t ws_size,
                              hipStream_t stream) {
    const float* E = (const float*)d_in[0];         // known_unit_emb [512][128]
    const float* W = (const float*)d_in[1];         // unit_aligner_weight [512][512]
    const float* convW = (const float*)d_in[2];     // [128][128][3]
    const float* convB = (const float*)d_in[3];     // [128]
    const float* insW = (const float*)d_in[4];
    const float* insB = (const float*)d_in[5];
    const int* ids = (const int*)d_in[6];           // [16000][12]
    const int* lens = (const int*)d_in[7];          // [16000]

    float* out = (float*)d_out;                                // FLOAT32 output
    float* sub_out = out;                                      // [V][L][512]
    float* ins_out = out + (size_t)V_ * L_ * LOST_;            // [V][L][512]
    float* align_out = out + 2ull * V_ * L_ * LOST_;           // [512][512]

    hipLaunchKernelGGL(k_wcv, dim3((2 * 128 * 384 + 255) / 256), dim3(256), 0, stream,
                       convW, insW);
    hipLaunchKernelGGL(k_lost, dim3(LOST_), dim3(128), 0, stream, W, E);
    hipLaunchKernelGGL(k_ulp, dim3(K_), dim3(512), 0, stream, E, align_out);
    hipLaunchKernelGGL(k_main, dim3(V_), dim3(256), 0, stream,
                       E, convB, insB, ids, lens, sub_out, ins_out);
}

// Round 22
// 878.021 us; speedup vs baseline: 50.6718x; 1.0262x over previous
//
#include <hip/hip_runtime.h>
#include <hip/hip_bf16.h>

#define V_ 16000
#define L_ 12
#define K_ 512
#define LOST_ 512
#define D_ 128

constexpr float CW = 0.5f;
constexpr float IDC = 3.5f;

typedef __attribute__((ext_vector_type(8))) short bf16x8;
typedef __attribute__((ext_vector_type(4))) float f32x4;

__device__ __align__(16) float g_lost[LOST_ * D_];    // lost_unit_emb f32 [512][128]
__device__ __align__(16) short g_lost_bf[LOST_ * D_]; // bf16 copy, [m][d] k-contiguous
__device__ __align__(16) float g_ulp[K_ * LOST_];     // unit_log_probs [512][512]
__device__ __align__(16) short g_wcv[2 * 128 * 384];  // conv weights bf16 [c][dout][t3*128+di]

__device__ __forceinline__ short f2b(float x) {
    __hip_bfloat16 h = __float2bfloat16(x);
    return *reinterpret_cast<short*>(&h);
}

// ---------------- kernel 0: repack conv weights -> bf16 [c][dout][k], k=t3*128+di
__global__ __launch_bounds__(256) void k_wcv(const float* __restrict__ wA,
                                             const float* __restrict__ wB) {
    int idx = blockIdx.x * 256 + threadIdx.x;
    if (idx >= 2 * 128 * 384) return;
    int di = idx % 128;
    int t3 = (idx / 128) % 3;
    int dout = (idx / 384) % 128;
    int c = idx / (128 * 384);
    const float* w = c ? wB : wA;
    g_wcv[idx] = f2b(w[((size_t)dout * 128 + di) * 3 + t3]);
}

// ---------------- kernel 1: lost_emb = aligner @ E (f32 + bf16)
__global__ __launch_bounds__(128) void k_lost(const float* __restrict__ W,
                                              const float* __restrict__ E) {
    int m = blockIdx.x;
    int d = threadIdx.x;
    const float* wrow = W + (size_t)m * K_;
    float acc = 0.f;
    for (int k = 0; k < K_; ++k) acc = fmaf(wrow[k], E[k * D_ + d], acc);
    g_lost[m * D_ + d] = acc;
    g_lost_bf[m * D_ + d] = f2b(acc);
}

// ---------------- kernel 2: unit_log_probs + alignment output (f32)
__global__ __launch_bounds__(512) void k_ulp(const float* __restrict__ E,
                                             float* __restrict__ align_out) {
    int k = blockIdx.x, t = threadIdx.x;
    __shared__ float e[D_];
    __shared__ float red[8];
    if (t < D_) e[t] = E[k * D_ + t];
    __syncthreads();
    const float* lm = g_lost + (size_t)t * D_;
    float acc = 0.f;
    for (int d = 0; d < D_; d += 4) {
        float4 lv = *(const float4*)(lm + d);
        acc = fmaf(e[d], lv.x, acc);
        acc = fmaf(e[d + 1], lv.y, acc);
        acc = fmaf(e[d + 2], lv.z, acc);
        acc = fmaf(e[d + 3], lv.w, acc);
    }
    int lane = t & 63, wid = t >> 6;
    float wm = acc;
    for (int off = 32; off; off >>= 1) wm = fmaxf(wm, __shfl_xor(wm, off, 64));
    if (lane == 0) red[wid] = wm;
    __syncthreads();
    float bm = red[0];
#pragma unroll
    for (int i = 1; i < 8; ++i) bm = fmaxf(bm, red[i]);
    __syncthreads();
    float s = expf(acc - bm);
    for (int off = 32; off; off >>= 1) s += __shfl_xor(s, off, 64);
    if (lane == 0) red[wid] = s;
    __syncthreads();
    float bs = 0.f;
#pragma unroll
    for (int i = 0; i < 8; ++i) bs += red[i];
    float lp = acc - bm - logf(bs);
    g_ulp[(size_t)k * LOST_ + t] = lp;
    align_out[(size_t)k * LOST_ + t] = expf(lp);
}

// swizzled column: keep low 3 bits, XOR granule (bits 3..6) with row&7
__device__ __forceinline__ int swz(int col, int row) {
    return (col & 7) | ((((col >> 3) ^ (row & 7)) & 15) << 3);
}

// ---------------- kernel 3: fused MFMA per-v kernel, coalesced epilogue
__global__ __launch_bounds__(256) void k_main(const float* __restrict__ E,
                                              const float* __restrict__ bA,
                                              const float* __restrict__ bB,
                                              const int* __restrict__ ids,
                                              const int* __restrict__ lens,
                                              float* __restrict__ sub_out,
                                              float* __restrict__ ins_out) {
    // shared arena: emb/ctx (phase 1-2) alias the f32 staging buffer (phase 3)
    __shared__ __align__(16) char shbuf[24 * 516 * 4];    // 49536 B
    short (*emb_bf)[128] = (short(*)[128])shbuf;          // 18 rows  (0..4607)
    short (*ctx_bf)[128] = (short(*)[128])(shbuf + 4608); // 32 rows  (4608..12799)
    float (*stage)[516] = (float(*)[516])shbuf;           // 24 rows f32, padded
    __shared__ float redm[4][16];
    __shared__ float reds[4][16];
    __shared__ int sids[12];
    __shared__ int slen;

    int v = blockIdx.x;
    int t = threadIdx.x;
    int lane = t & 63, w = t >> 6;
    int l15 = lane & 15, kg = lane >> 4;

    if (t < 12) sids[t] = min(max(ids[v * 12 + t], 0), 511);
    if (t == 12) slen = min(max(lens[v], 0), 12);
    for (int i = t; i < 8 * 128; i += 256) ctx_bf[24 + (i >> 7)][i & 127] = 0;
    __syncthreads();
    int len = slen;

    // ---- gather masked emb rows -> bf16 swizzled LDS
    for (int i = t; i < 18 * 128; i += 256) {
        int row = i >> 7, di = i & 127;
        float val = 0.f;
        if (row >= 1 && row <= 12) {
            int pos = row - 1;
            if (pos < len) val = E[(size_t)sids[pos] * D_ + di];
        }
        emb_bf[row][swz(di, row)] = f2b(val);
    }
    __syncthreads();

    // ---- conv via MFMA: wave w -> c = w&1, dout-tiles dtb..dtb+3
    {
        int c = w & 1;
        int dtb = (w >> 1) * 4;
        f32x4 acc[4];
#pragma unroll
        for (int i = 0; i < 4; ++i) acc[i] = (f32x4){0.f, 0.f, 0.f, 0.f};
        const short* wb = g_wcv + (size_t)c * 128 * 384;
#pragma unroll
        for (int kk = 0; kk < 12; ++kk) {
            int t3 = kk >> 2;
            int row = l15 + t3;
            int g = (((kk & 3) * 4 + kg) ^ (row & 7)) & 15;
            bf16x8 af = *(const bf16x8*)&emb_bf[row][g << 3];
#pragma unroll
            for (int i = 0; i < 4; ++i) {
                int n = (dtb + i) * 16 + l15;
                bf16x8 bf = *(const bf16x8*)(wb + (size_t)n * 384 + kk * 32 + kg * 8);
                acc[i] = __builtin_amdgcn_mfma_f32_16x16x32_bf16(af, bf, acc[i], 0, 0, 0);
            }
        }
#pragma unroll
        for (int i = 0; i < 4; ++i) {
            int dout = (dtb + i) * 16 + l15;
            float bias = (c ? bB : bA)[dout];
#pragma unroll
            for (int reg = 0; reg < 4; ++reg) {
                int lrow = kg * 4 + reg;
                if (lrow < 12) {
                    int r = c * 12 + lrow;
                    ctx_bf[r][swz(dout, r)] = f2b(acc[i][reg] + bias);
                }
            }
        }
    }
    __syncthreads();

    // ---- logits via MFMA: wave w -> Mtile mt = w&1, N-half nh = w>>1
    int mt = w & 1, nh = w >> 1;
    f32x4 lacc[16];
#pragma unroll
    for (int i = 0; i < 16; ++i) lacc[i] = (f32x4){0.f, 0.f, 0.f, 0.f};
    int arow = mt * 16 + l15;
#pragma unroll
    for (int kk = 0; kk < 4; ++kk) {
        int g = ((kk * 4 + kg) ^ (arow & 7)) & 15;
        bf16x8 af = *(const bf16x8*)&ctx_bf[arow][g << 3];
        const short* lb = g_lost_bf + kk * 32 + kg * 8;
#pragma unroll
        for (int i = 0; i < 16; ++i) {
            int n = (nh * 16 + i) * 16 + l15;
            bf16x8 bf = *(const bf16x8*)(lb + (size_t)n * 128);
            lacc[i] = __builtin_amdgcn_mfma_f32_16x16x32_bf16(af, bf, lacc[i], 0, 0, 0);
        }
    }

    // ---- softmax (rows r = mt*16 + kg*4 + reg; col halves split across wave pair)
    float fm[4], norm[4];
#pragma unroll
    for (int reg = 0; reg < 4; ++reg) {
        float m = lacc[0][reg];
#pragma unroll
        for (int i = 1; i < 16; ++i) m = fmaxf(m, lacc[i][reg]);
        for (int off = 1; off < 16; off <<= 1) m = fmaxf(m, __shfl_xor(m, off, 64));
        if (l15 == 0) redm[w][kg * 4 + reg] = m;
    }
    __syncthreads();   // also: all waves done reading ctx/emb LDS
#pragma unroll
    for (int reg = 0; reg < 4; ++reg)
        fm[reg] = fmaxf(redm[w][kg * 4 + reg], redm[w ^ 2][kg * 4 + reg]);
#pragma unroll
    for (int reg = 0; reg < 4; ++reg) {
        float s = 0.f;
#pragma unroll
        for (int i = 0; i < 16; ++i) s += __expf(lacc[i][reg] - fm[reg]);
        for (int off = 1; off < 16; off <<= 1) s += __shfl_xor(s, off, 64);
        if (l15 == 0) reds[w][kg * 4 + reg] = s;
    }
    __syncthreads();
#pragma unroll
    for (int reg = 0; reg < 4; ++reg)
        norm[reg] = fm[reg] + __logf(reds[w][kg * 4 + reg] + reds[w ^ 2][kg * 4 + reg]);

    // ---- stage fragments into f32 LDS (aliases emb/ctx — all reads done)
#pragma unroll
    for (int reg = 0; reg < 4; ++reg) {
        int r = mt * 16 + kg * 4 + reg;
        if (r >= 24) continue;
        float nrm = norm[reg];
        bool isSub = (r < 12);
#pragma unroll
        for (int i = 0; i < 16; ++i) {
            int col = nh * 256 + i * 16 + l15;
            float lp = lacc[i][reg] - nrm;
            stage[r][col] = isSub ? (-CW * lp) : (IDC - CW * lp);
        }
    }
    __syncthreads();

    // ---- coalesced streaming output: float4 rows
    // sub rows 0..11: out = stage - 0.5*g_ulp[sids[r]]
#pragma unroll
    for (int j = 0; j < 6; ++j) {
        int idx = t + j * 256;            // 0..1535 float4 chunks
        int r = idx >> 7, q = idx & 127;
        float4 sv = *(const float4*)&stage[r][q * 4];
        const float4 gv = *(const float4*)(g_ulp + (size_t)sids[r] * LOST_ + q * 4);
        float4 o;
        o.x = sv.x - 0.5f * gv.x;
        o.y = sv.y - 0.5f * gv.y;
        o.z = sv.z - 0.5f * gv.z;
        o.w = sv.w - 0.5f * gv.w;
        *(float4*)&sub_out[((size_t)v * 12 + r) * 512 + q * 4] = o;
    }
    // ins rows 12..23
#pragma unroll
    for (int j = 0; j < 6; ++j) {
        int idx = t + j * 256;
        int r = idx >> 7, q = idx & 127;
        float4 sv = *(const float4*)&stage[12 + r][q * 4];
        *(float4*)&ins_out[((size_t)v * 12 + r) * 512 + q * 4] = sv;
    }
}

extern "C" void kernel_launch(void* const* d_in, const int* in_sizes, int n_in,
                              void* d_out, int out_size, void* d_ws, size_t ws_size,
                              hipStream_t stream) {
    const float* E = (const float*)d_in[0];         // known_unit_emb [512][128]
    const float* W = (const float*)d_in[1];         // unit_aligner_weight [512][512]
    const float* convW = (const float*)d_in[2];     // [128][128][3]
    const float* convB = (const float*)d_in[3];     // [128]
    const float* insW = (const float*)d_in[4];
    const float* insB = (const float*)d_in[5];
    const int* ids = (const int*)d_in[6];           // [16000][12]
    const int* lens = (const int*)d_in[7];          // [16000]

    float* out = (float*)d_out;                                // FLOAT32 output
    float* sub_out = out;                                      // [V][L][512]
    float* ins_out = out + (size_t)V_ * L_ * LOST_;            // [V][L][512]
    float* align_out = out + 2ull * V_ * L_ * LOST_;           // [512][512]

    hipLaunchKernelGGL(k_wcv, dim3((2 * 128 * 384 + 255) / 256), dim3(256), 0, stream,
                       convW, insW);
    hipLaunchKernelGGL(k_lost, dim3(LOST_), dim3(128), 0, stream, W, E);
    hipLaunchKernelGGL(k_ulp, dim3(K_), dim3(512), 0, stream, E, align_out);
    hipLaunchKernelGGL(k_main, dim3(V_), dim3(256), 0, stream,
                       E, convB, insB, ids, lens, sub_out, ins_out);
}